// Round 4
// baseline (19183.340 us; speedup 1.0000x reference)
//
#include <hip/hip_runtime.h>
#include <hip/hip_bf16.h>

#define SEQ    256
#define BATCH  64
#define EMB    256
#define HID    1024
#define GATES  3072   // 3*HID
#define NCLS   128
#define TCH    16                 // time chunk
#define ROWS   (TCH * BATCH)      // 1024 rows per chunk

typedef __attribute__((ext_vector_type(8))) short bf16x8;
typedef __attribute__((ext_vector_type(4))) float f32x4;

__device__ inline unsigned short f2bf(float x) {
    union { float f; unsigned int u; } v; v.f = x;
    v.u += 0x7fffu + ((v.u >> 16) & 1u);   // RNE
    return (unsigned short)(v.u >> 16);
}

// ---------------------------------------------------------------------------
__global__ void conv_bf16(const float* __restrict__ in, unsigned short* __restrict__ out, int n) {
    int i = (blockIdx.x * 256 + threadIdx.x) * 4;
    if (i < n) {
        float4 v = *(const float4*)(in + i);
        out[i + 0] = f2bf(v.x); out[i + 1] = f2bf(v.y);
        out[i + 2] = f2bf(v.z); out[i + 3] = f2bf(v.w);
    }
}

// ---------------------------------------------------------------------------
// bf16 MFMA GEMM: C[M,N] = A[M,K] * Bw[N,K]^T + bias[N]  (as round 3, proven)
// ---------------------------------------------------------------------------
template <int MODE>
__global__ void gemm_mfma(const unsigned short* __restrict__ A,
                          const unsigned short* __restrict__ Bw,
                          const float* __restrict__ bias, float* __restrict__ Cout,
                          int N, int K, const int* __restrict__ xidx,
                          const unsigned short* __restrict__ emb, int row_base) {
    const int tid = threadIdx.x;
    const int w = tid >> 6, l = tid & 63;
    const int m0 = blockIdx.x * 64 + w * 16;
    const int n0 = blockIdx.y * 64;
    const int la = l & 15, lk = (l >> 4) * 8;

    const unsigned short* arow;
    if (MODE == 1) {
        int g = row_base + m0 + la;
        int s = g >> 6, b = g & 63;
        arow = emb + (size_t)xidx[b * SEQ + s] * K + lk;
    } else {
        arow = A + (size_t)(m0 + la) * K + lk;
    }
    const unsigned short* brow = Bw + (size_t)(n0 + la) * K + lk;

    f32x4 acc[4] = {};
    for (int k = 0; k < K; k += 32) {
        bf16x8 a = *(const bf16x8*)(arow + k);
#pragma unroll
        for (int nt = 0; nt < 4; ++nt) {
            bf16x8 bb = *(const bf16x8*)(brow + (size_t)nt * 16 * K + k);
            acc[nt] = __builtin_amdgcn_mfma_f32_16x16x32_bf16(a, bb, acc[nt], 0, 0, 0);
        }
    }

    const int rbase = (l >> 4) * 4;
#pragma unroll
    for (int nt = 0; nt < 4; ++nt) {
        int colg = n0 + nt * 16 + la;
        float bsv = bias[colg];
#pragma unroll
        for (int i = 0; i < 4; ++i) {
            int rowg = m0 + rbase + i;
            float v = acc[nt][i] + bsv;
            if (MODE == 2) {
                int g = row_base + rowg;
                int s = g >> 6, b = g & 63;
                Cout[((size_t)(b * SEQ + s)) * NCLS + colg] = v;
            } else {
                Cout[(size_t)rowg * N + colg] = v;
            }
        }
    }
}

// ---------------------------------------------------------------------------
// Persistent GRU chunk kernel: all TCH steps of one layer in ONE launch.
// grid = 256 blocks (bg = blockIdx.x>>6 batch-group of 16, jt = &63 j-tile of 16).
// w_hh slice (3 gates x 16 rows x 1024) staged in LDS once, XOR-swizzled.
// h: bf16 ping/pong global buffers (hb0 = entry & even-step source).
// f32 state for own (b,j) kept in a register across steps.
// Per-group 64-block monotonic atomic barrier between steps.
// ---------------------------------------------------------------------------
__global__ __launch_bounds__(256, 1)
void gru_chunk(const float* __restrict__ gi,
               const unsigned short* __restrict__ whb,   // [3072][1024] bf16
               const float* __restrict__ b_hh,
               float* __restrict__ h_f,                  // [64][1024] f32 persistent
               unsigned short* __restrict__ hb0,         // ping (entry state)
               unsigned short* __restrict__ hb1,         // pong
               unsigned short* __restrict__ outseq,      // [TCH*64][1024] bf16
               int* __restrict__ bar) {                  // 4 ints (this launch's slots)
    extern __shared__ char smem[];
    unsigned short* wlds = (unsigned short*)smem;             // 96 KB swizzled
    float* sg = (float*)(smem + 3 * 16 * HID * 2);            // 3*256 f32

    const int bg = blockIdx.x >> 6;
    const int jt = blockIdx.x & 63;
    const int b0 = bg * 16, j0 = jt * 16;
    const int tid = threadIdx.x;
    const int w = tid >> 6, l = tid & 63;

    // ---- stage w slice into LDS (once), swizzled: byte ^= (row&7)<<4 ----
#pragma unroll
    for (int c = 0; c < 24; ++c) {
        int u = tid + 256 * c;            // 16B-unit id, 0..6143
        int row = u >> 7;                 // 0..47  (g*16 + r)
        int off16 = u & 127;              // 16B offset within row
        int g = row >> 4, r = row & 15;
        const unsigned short* src = whb + (size_t)(g * HID + j0 + r) * HID + off16 * 8;
        int byte = row * 2048 + ((off16 * 16) ^ ((r & 7) << 4));
        *(bf16x8*)(smem + byte) = *(const bf16x8*)src;
    }

    // ---- own f32 state + biases ----
    const int prow = tid >> 4, pcol = tid & 15;
    const int pb = b0 + prow, pj = j0 + pcol;
    float hp = h_f[(size_t)pb * HID + pj];
    const float bhr = b_hh[pj], bhz = b_hh[HID + pj], bhn = b_hh[2 * HID + pj];

    __syncthreads();

    const unsigned short* hbuf[2] = {hb0, hb1};

    for (int t = 0; t < TCH; ++t) {
        const unsigned short* hin = hbuf[t & 1];
        unsigned short* hout = (unsigned short*)hbuf[(t + 1) & 1];

        if (w < 3) {
            f32x4 acc = {};
            const int r = l & 15;
            const unsigned short* hrow = hin + (size_t)(b0 + r) * HID + ((l >> 4) * 8);
            const int rowbyte = (w * 16 + r) * 2048;
            const int sw = (r & 7) << 4;
            const int kq = (l >> 4) * 16;
#pragma unroll
            for (int ks = 0; ks < 32; ++ks) {
                bf16x8 a = *(const bf16x8*)(hrow + ks * 32);
                bf16x8 b = *(const bf16x8*)(smem + rowbyte + ((ks * 64 + kq) ^ sw));
                acc = __builtin_amdgcn_mfma_f32_16x16x32_bf16(a, b, acc, 0, 0, 0);
            }
            const int col = l & 15, rbase = (l >> 4) * 4;
#pragma unroll
            for (int i = 0; i < 4; ++i) sg[w * 256 + (rbase + i) * 16 + col] = acc[i];
        }
        __syncthreads();

        // ---- pointwise (all 256 threads, own (b,j)) ----
        const float* git = gi + ((size_t)(t * BATCH + pb)) * GATES;
        float ghr = sg[0 * 256 + tid] + bhr;
        float ghz = sg[1 * 256 + tid] + bhz;
        float ghn = sg[2 * 256 + tid] + bhn;
        float rr = 1.f / (1.f + __expf(-(git[pj] + ghr)));
        float zz = 1.f / (1.f + __expf(-(git[HID + pj] + ghz)));
        float nn = tanhf(git[2 * HID + pj] + rr * ghn);
        hp = (1.f - zz) * nn + zz * hp;
        unsigned short hb = f2bf(hp);
        hout[(size_t)pb * HID + pj] = hb;
        outseq[((size_t)(t * BATCH + pb)) * HID + pj] = hb;

        if (t < TCH - 1) {
            // ---- per-group barrier (64 blocks), monotonic counter ----
            __syncthreads();                       // all stores issued + sg reads done
            if (tid == 0) {
                __threadfence();                   // release block's h writes
                __hip_atomic_fetch_add(bar + bg, 1, __ATOMIC_RELEASE, __HIP_MEMORY_SCOPE_AGENT);
                while (__hip_atomic_load(bar + bg, __ATOMIC_ACQUIRE, __HIP_MEMORY_SCOPE_AGENT)
                       < 64 * (t + 1)) {}
            }
            __syncthreads();
            __threadfence();                       // acquire for all threads
        }
    }

    h_f[(size_t)pb * HID + pj] = hp;
}

// ---------------------------------------------------------------------------
extern "C" void kernel_launch(void* const* d_in, const int* in_sizes, int n_in,
                              void* d_out, int out_size, void* d_ws, size_t ws_size,
                              hipStream_t stream) {
    const int*   x      = (const int*)d_in[0];
    const float* hs     = (const float*)d_in[1];
    const float* emb    = (const float*)d_in[2];
    const float* w_ih0  = (const float*)d_in[3];
    const float* w_hh0  = (const float*)d_in[4];
    const float* b_ih0  = (const float*)d_in[5];
    const float* b_hh0  = (const float*)d_in[6];
    const float* w_ih1  = (const float*)d_in[7];
    const float* w_hh1  = (const float*)d_in[8];
    const float* b_ih1  = (const float*)d_in[9];
    const float* b_hh1  = (const float*)d_in[10];
    const float* w_proj = (const float*)d_in[11];
    const float* b_proj = (const float*)d_in[12];

    float* logits = (float*)d_out;                       // [B*S, 128] f32
    float* hT     = logits + (size_t)SEQ * BATCH * NCLS; // [2, 64, 1024] f32

    // ---- workspace layout ----
    char* p = (char*)d_ws;
    float* gi = (float*)p;                      p += (size_t)ROWS * GATES * 4;   // 12.6 MB
    float* h0f = (float*)p;                     p += 65536 * 4;
    float* h1f = (float*)p;                     p += 65536 * 4;
    unsigned short* h0b0 = (unsigned short*)p;  p += 65536 * 2;
    unsigned short* h0b1 = (unsigned short*)p;  p += 65536 * 2;
    unsigned short* h1b0 = (unsigned short*)p;  p += 65536 * 2;
    unsigned short* h1b1 = (unsigned short*)p;  p += 65536 * 2;
    unsigned short* out0b = (unsigned short*)p; p += (size_t)ROWS * HID * 2;     // 2.1 MB
    unsigned short* out1b = (unsigned short*)p; p += (size_t)ROWS * HID * 2;     // 2.1 MB
    unsigned short* embB  = (unsigned short*)p; p += (size_t)NCLS * EMB * 2;
    unsigned short* wih0B = (unsigned short*)p; p += (size_t)GATES * EMB * 2;
    unsigned short* whh0B = (unsigned short*)p; p += (size_t)GATES * HID * 2;
    unsigned short* wih1B = (unsigned short*)p; p += (size_t)GATES * HID * 2;
    unsigned short* whh1B = (unsigned short*)p; p += (size_t)GATES * HID * 2;
    unsigned short* wprojB = (unsigned short*)p; p += (size_t)NCLS * HID * 2;
    int* bar = (int*)p;                         p += 128 * 4;   // 16 chunks x 2 layers x 4 groups

    // allow >64KB dynamic LDS for the persistent kernel
    hipFuncSetAttribute((const void*)gru_chunk,
                        hipFuncAttributeMaxDynamicSharedMemorySize, 112 * 1024);
    const int GRU_LDS = 3 * 16 * HID * 2 + 3 * 256 * 4;   // 98304 + 3072

    // ---- barrier counters: reset every replay ----
    hipMemsetAsync(bar, 0, 128 * 4, stream);

    // ---- one-time weight conversions ----
    conv_bf16<<<(NCLS * EMB) / 1024, 256, 0, stream>>>(emb, embB, NCLS * EMB);
    conv_bf16<<<(GATES * EMB) / 1024, 256, 0, stream>>>(w_ih0, wih0B, GATES * EMB);
    conv_bf16<<<(GATES * HID) / 1024, 256, 0, stream>>>(w_hh0, whh0B, GATES * HID);
    conv_bf16<<<(GATES * HID) / 1024, 256, 0, stream>>>(w_ih1, wih1B, GATES * HID);
    conv_bf16<<<(GATES * HID) / 1024, 256, 0, stream>>>(w_hh1, whh1B, GATES * HID);
    conv_bf16<<<(NCLS * HID) / 1024, 256, 0, stream>>>(w_proj, wprojB, NCLS * HID);

    // ---- init hidden state ----
    hipMemcpyAsync(h0f, hs, 65536 * 4, hipMemcpyDeviceToDevice, stream);
    hipMemcpyAsync(h1f, hs + 65536, 65536 * 4, hipMemcpyDeviceToDevice, stream);
    conv_bf16<<<64, 256, 0, stream>>>(hs, h0b0, 65536);
    conv_bf16<<<64, 256, 0, stream>>>(hs + 65536, h1b0, 65536);

    dim3 gg(ROWS / 64, GATES / 64);   // (16, 48)
    dim3 gp(ROWS / 64, NCLS / 64);    // (16, 2)

    for (int c = 0; c < SEQ / TCH; ++c) {
        int row_base = c * ROWS;

        // gi = embed[x] @ w_ih0^T + b_ih0 (gathered A)
        gemm_mfma<1><<<gg, 256, 0, stream>>>(nullptr, wih0B, b_ih0, gi, GATES, EMB, x, embB, row_base);

        // layer 0: 16 steps, one persistent launch
        gru_chunk<<<256, 256, GRU_LDS, stream>>>(gi, whh0B, b_hh0, h0f, h0b0, h0b1,
                                                 out0b, bar + (c * 2 + 0) * 4);

        // gi = out0 @ w_ih1^T + b_ih1
        gemm_mfma<0><<<gg, 256, 0, stream>>>(out0b, wih1B, b_ih1, gi, GATES, HID, nullptr, nullptr, 0);

        // layer 1: 16 steps, one persistent launch
        gru_chunk<<<256, 256, GRU_LDS, stream>>>(gi, whh1B, b_hh1, h1f, h1b0, h1b1,
                                                 out1b, bar + (c * 2 + 1) * 4);

        // logits chunk = out1 @ w_proj^T + b_proj (remapped store)
        gemm_mfma<2><<<gp, 256, 0, stream>>>(out1b, wprojB, b_proj, logits, NCLS, HID, nullptr, nullptr, row_base);
    }

    hipMemcpyAsync(hT, h0f, 65536 * 4, hipMemcpyDeviceToDevice, stream);
    hipMemcpyAsync(hT + 65536, h1f, 65536 * 4, hipMemcpyDeviceToDevice, stream);
}